// Round 6
// baseline (517.207 us; speedup 1.0000x reference)
//
#include <hip/hip_runtime.h>
#include <hip/hip_bf16.h>
#include <math.h>

// ---------------------------------------------------------------------------
// Autoformer encoder layer, MI355X (gfx950).
// B=4, L=4096, D=512, H=8, dk=64, F=2048, MA=25, top_k=8.
// GEMMs in fp16 MFMA (16x16x32_f16), fp32 accumulate; fp16 intermediates.
// ---------------------------------------------------------------------------

typedef _Float16 half8_t __attribute__((ext_vector_type(8)));
typedef _Float16 half4_t __attribute__((ext_vector_type(4)));
typedef float    f32x4_t __attribute__((ext_vector_type(4)));

__device__ __forceinline__ void gl_lds16(const _Float16* src, _Float16* dst) {
  __builtin_amdgcn_global_load_lds(
      (const __attribute__((address_space(1))) unsigned int*)(const void*)src,
      (__attribute__((address_space(3))) unsigned int*)(void*)dst, 16, 0, 0);
}

// ---------------------------------------------------------------------------
// Generic fp16 GEMM:  out[M,N] = A[M,K] @ Bt[N,K]^T + bias, optional GELU.
// 128x128 tile, BK=64, 256 threads (4 waves, 2x2), XOR-swizzled LDS.
// Swapped-operand epilogue (N on reg axis -> vector stores).
// ---------------------------------------------------------------------------
template<bool OUT16, bool DOGELU>
__global__ __launch_bounds__(256) void gemm_f16k(
    const _Float16* __restrict__ A, const _Float16* __restrict__ Bt,
    const float* __restrict__ bs0, const float* __restrict__ bs1,
    const float* __restrict__ bs2, int segShift,
    void* __restrict__ outp, int M, int N, int K)
{
  __shared__ _Float16 As[128 * 64];
  __shared__ _Float16 Bs[128 * 64];
  const int tid = threadIdx.x, lane = tid & 63, w = tid >> 6;
  const int wr = w >> 1, wc = w & 1;
  const int m0 = blockIdx.x * 128, n0 = blockIdx.y * 128;

  f32x4_t acc[4][4];
  #pragma unroll
  for (int i = 0; i < 4; ++i)
    #pragma unroll
    for (int j = 0; j < 4; ++j) acc[i][j] = (f32x4_t){0.f, 0.f, 0.f, 0.f};

  const _Float16* Ab = A + (size_t)m0 * K;
  const _Float16* Bb = Bt + (size_t)n0 * K;

  for (int k0 = 0; k0 < K; k0 += 64) {
    #pragma unroll
    for (int q = 0; q < 4; ++q) {
      int off = ((w << 2) + q) << 10;
      int row = (off >> 7) + (lane >> 3);
      int sl  = (lane & 7) ^ (row & 7);
      gl_lds16(Ab + (size_t)row * K + k0 + (sl << 3), As + (off >> 1));
    }
    #pragma unroll
    for (int q = 0; q < 4; ++q) {
      int off = ((w << 2) + q) << 10;
      int row = (off >> 7) + (lane >> 3);
      int sl  = (lane & 7) ^ (row & 7);
      gl_lds16(Bb + (size_t)row * K + k0 + (sl << 3), Bs + (off >> 1));
    }
    __syncthreads();

    #pragma unroll
    for (int kk = 0; kk < 2; ++kk) {
      half8_t af[4], bf[4];
      #pragma unroll
      for (int mi = 0; mi < 4; ++mi) {
        int row = wr * 64 + mi * 16 + (lane & 15);
        int sl  = ((kk << 2) + (lane >> 4)) ^ (row & 7);
        af[mi] = *(const half8_t*)(As + row * 64 + (sl << 3));
      }
      #pragma unroll
      for (int ni = 0; ni < 4; ++ni) {
        int row = wc * 64 + ni * 16 + (lane & 15);
        int sl  = ((kk << 2) + (lane >> 4)) ^ (row & 7);
        bf[ni] = *(const half8_t*)(Bs + row * 64 + (sl << 3));
      }
      #pragma unroll
      for (int mi = 0; mi < 4; ++mi)
        #pragma unroll
        for (int ni = 0; ni < 4; ++ni)
          acc[mi][ni] = __builtin_amdgcn_mfma_f32_16x16x32_f16(
              bf[ni], af[mi], acc[mi][ni], 0, 0, 0);   // swapped: N on reg axis
    }
    __syncthreads();
  }

  int seg = n0 >> segShift; if (seg > 2) seg = 2;
  const float* bias = seg == 0 ? bs0 : (seg == 1 ? bs1 : bs2);
  const unsigned bmask = (segShift >= 31) ? 0xffffffffu : ((1u << segShift) - 1u);

  #pragma unroll
  for (int ni = 0; ni < 4; ++ni) {
    int n = n0 + wc * 64 + ni * 16 + ((lane >> 4) << 2);
    f32x4_t b4 = *(const f32x4_t*)(bias + (n & bmask));
    #pragma unroll
    for (int mi = 0; mi < 4; ++mi) {
      int m = m0 + wr * 64 + mi * 16 + (lane & 15);
      f32x4_t v = acc[mi][ni] + b4;
      if (DOGELU) {
        #pragma unroll
        for (int r = 0; r < 4; ++r)
          v[r] = 0.5f * v[r] * (1.f + erff(v[r] * 0.70710678118654752f));
      }
      if (OUT16) {
        half4_t o;
        o[0] = (_Float16)v[0]; o[1] = (_Float16)v[1];
        o[2] = (_Float16)v[2]; o[3] = (_Float16)v[3];
        *(half4_t*)((_Float16*)outp + (size_t)m * N + n) = o;
      } else {
        *(f32x4_t*)((float*)outp + (size_t)m * N + n) = v;
      }
    }
  }
}

// ---------------------------------------------------------------------------
// Autocorrelation v6: block owns (b, h, tau-window [64T, 64T+64)).
// WAVE-PER-J: wave w computes J = 4i+w entirely (full 64x64 tile, acc[4][4]),
// so each staged tile is read by exactly ONE wave (halves LDS read traffic).
// Per iteration: stage 8 tiles (64KB) -> barrier -> each wave 16 ds_read_b128
// + 32 MFMA -> barrier. Epilogue: waves serially accumulate into diagonal-
// major Gd, then verified diagonal extraction. No atomics.
// ---------------------------------------------------------------------------
__global__ __launch_bounds__(256) void corr_gram6(
    const _Float16* __restrict__ QKV,
    float* __restrict__ corrP, float* __restrict__ corrN)
{
  __shared__ __attribute__((aligned(16))) char smem[65536];
  _Float16* tiles = (_Float16*)smem;          // 8 tiles x 4096 halfs
  float*    Gd    = (float*)smem;             // [128][68] after loop

  const int tid = threadIdx.x, lane = tid & 63, w = tid >> 6;
  const int p  = blockIdx.x;
  const int lg = ((p & 7) << 8) + (p >> 3);   // XCD-chunked swizzle
  const int T = lg & 63, h = (lg >> 6) & 7, b = lg >> 9;

  // hoisted staging offsets (2 issues per wave per tile)
  size_t qoff[2], koff[2]; int loff[2];
  #pragma unroll
  for (int q_ = 0; q_ < 2; ++q_) {
    int off_ = ((w << 1) + q_) << 10;
    int row_ = (off_ >> 7) + (lane >> 3);
    int sl_  = (lane & 7) ^ (row_ & 7);
    loff[q_] = off_ >> 1;
    qoff[q_] = (size_t)row_ * 1536 + (sl_ << 3) + h * 64;
    koff[q_] = qoff[q_] + 512;
  }
  const size_t bbase = (size_t)b * 4096 * 1536;

  // hoisted frag LDS offsets (identical formula for A and B)
  int foff[4][2];
  #pragma unroll
  for (int mi = 0; mi < 4; ++mi) {
    int row = (mi << 4) + (lane & 15);
    #pragma unroll
    for (int kk = 0; kk < 2; ++kk) {
      int sl = ((kk << 2) + (lane >> 4)) ^ (row & 7);
      foff[mi][kk] = row * 64 + (sl << 3);
    }
  }

  f32x4_t acc[4][4];
  #pragma unroll
  for (int i = 0; i < 4; ++i)
    #pragma unroll
    for (int j = 0; j < 4; ++j) acc[i][j] = (f32x4_t){0.f, 0.f, 0.f, 0.f};

  for (int i = 0; i < 16; ++i) {
    const int J0 = i << 2;
    #pragma unroll
    for (int t = 0; t < 4; ++t) {
      const size_t qb = bbase + (size_t)((T + J0 + t) & 63) * 98304;
      gl_lds16(QKV + qb + qoff[0], tiles + t * 4096 + loff[0]);
      gl_lds16(QKV + qb + qoff[1], tiles + t * 4096 + loff[1]);
      const size_t kb = bbase + (size_t)(J0 + t) * 98304;
      gl_lds16(QKV + kb + koff[0], tiles + (4 + t) * 4096 + loff[0]);
      gl_lds16(QKV + kb + koff[1], tiles + (4 + t) * 4096 + loff[1]);
    }
    __syncthreads();                           // tiles landed (vmcnt drained)

    const _Float16* Qb = tiles + w * 4096;
    const _Float16* Kb = tiles + (4 + w) * 4096;
    half8_t a0[4], a1[4], b0v[4], b1v[4];
    #pragma unroll
    for (int mi = 0; mi < 4; ++mi) {
      a0[mi] = *(const half8_t*)(Qb + foff[mi][0]);
      a1[mi] = *(const half8_t*)(Qb + foff[mi][1]);
    }
    #pragma unroll
    for (int ni = 0; ni < 4; ++ni) {
      b0v[ni] = *(const half8_t*)(Kb + foff[ni][0]);
      b1v[ni] = *(const half8_t*)(Kb + foff[ni][1]);
    }
    #pragma unroll
    for (int mi = 0; mi < 4; ++mi)
      #pragma unroll
      for (int ni = 0; ni < 4; ++ni) {
        acc[mi][ni] = __builtin_amdgcn_mfma_f32_16x16x32_f16(
            a0[mi], b0v[ni], acc[mi][ni], 0, 0, 0);
        acc[mi][ni] = __builtin_amdgcn_mfma_f32_16x16x32_f16(
            a1[mi], b1v[ni], acc[mi][ni], 0, 0, 0);
      }
    __syncthreads();                           // reads done before next stage
  }

  // ---- diagonal accumulation: Gd zero, then waves add serially
  for (int idx = tid; idx < 128 * 68; idx += 256) Gd[idx] = 0.f;
  __syncthreads();
  #pragma unroll 1
  for (int wv = 0; wv < 4; ++wv) {
    if (w == wv) {
      #pragma unroll
      for (int mi = 0; mi < 4; ++mi)
        #pragma unroll
        for (int ni = 0; ni < 4; ++ni)
          #pragma unroll
          for (int r = 0; r < 4; ++r) {
            int row = (mi << 4) + ((lane >> 4) << 2) + r;
            int col = (ni << 4) + (lane & 15);
            Gd[(row - col + 64) * 68 + col] += acc[mi][ni][r];
          }
    }
    __syncthreads();
  }

  float s;
  {
    const float* gp = &Gd[(tid >> 1) * 68 + ((tid & 1) << 5)];
    f32x4_t x0 = *(const f32x4_t*)gp        + *(const f32x4_t*)(gp + 4);
    f32x4_t x1 = *(const f32x4_t*)(gp + 8)  + *(const f32x4_t*)(gp + 12);
    f32x4_t x2 = *(const f32x4_t*)(gp + 16) + *(const f32x4_t*)(gp + 20);
    f32x4_t x3 = *(const f32x4_t*)(gp + 24) + *(const f32x4_t*)(gp + 28);
    x0 += x1; x2 += x3; x0 += x2;
    s = x0[0] + x0[1] + x0[2] + x0[3];
  }
  s += __shfl_xor(s, 1);
  if ((tid & 1) == 0) {
    const size_t bh = (size_t)(b * 8 + h) << 12;
    int v = tid >> 1;
    if (v == 0) {
      corrN[bh + (T << 6)] = 0.f;          // tau==0 mod 64: no negative part
    } else {
      int d = v - 64;
      int tau = ((T << 6) + d) & 4095;
      if (d >= 0) corrP[bh + tau] = s;
      else        corrN[bh + tau] = s;
    }
  }
}

// ---------------------------------------------------------------------------
// Top-8 + softmax per (b,h). corr = corrP + corrN. Lowest-index tie-break.
// ---------------------------------------------------------------------------
__global__ __launch_bounds__(256) void topk_softmax(
    const float* __restrict__ corrP, const float* __restrict__ corrN,
    float* __restrict__ tw, int* __restrict__ ti)
{
  __shared__ float vals[4096];
  __shared__ float wvv[4]; __shared__ int wii[4];
  __shared__ float rv[8]; __shared__ int ri[8];
  const int tid = threadIdx.x;
  const int bh = blockIdx.x;
  const float* cp = corrP + (size_t)bh * 4096;
  const float* cn = corrN + (size_t)bh * 4096;
  for (int i = tid; i < 4096; i += 256) vals[i] = cp[i] + cn[i];
  __syncthreads();

  for (int it = 0; it < 8; ++it) {
    float bv = -3.4e38f; int bi = 1 << 30;
    for (int i = tid; i < 4096; i += 256) {
      float v = vals[i];
      if (v > bv) { bv = v; bi = i; }
    }
    #pragma unroll
    for (int o = 32; o > 0; o >>= 1) {
      float ov = __shfl_down(bv, o);
      int   oi = __shfl_down(bi, o);
      if (ov > bv || (ov == bv && oi < bi)) { bv = ov; bi = oi; }
    }
    if ((tid & 63) == 0) { wvv[tid >> 6] = bv; wii[tid >> 6] = bi; }
    __syncthreads();
    if (tid == 0) {
      for (int k = 1; k < 4; ++k)
        if (wvv[k] > bv || (wvv[k] == bv && wii[k] < bi)) { bv = wvv[k]; bi = wii[k]; }
      rv[it] = bv; ri[it] = bi; vals[bi] = -3.4e38f;
    }
    __syncthreads();
  }

  if (tid == 0) {
    float m = rv[0] * (1.f / 64.f);          // corr_mean = corr/dk; rv[0] is max
    float e[8]; float s = 0.f;
    for (int k = 0; k < 8; ++k) { e[k] = expf(rv[k] * (1.f / 64.f) - m); s += e[k]; }
    float inv = 1.f / s;
    for (int k = 0; k < 8; ++k) { tw[bh * 8 + k] = e[k] * inv; ti[bh * 8 + k] = ri[k]; }
  }
}

// ---------------------------------------------------------------------------
// out[b,l,h*64+d] = sum_k tw[k] * V[b,(l+ti[k])%L, h*64+d]; V inside QKV
// (stride 1536, col offset 1024). Output fp16 [16384][512].
// ---------------------------------------------------------------------------
__global__ __launch_bounds__(256) void gather_attn(
    const _Float16* __restrict__ QKV, const float* __restrict__ tw,
    const int* __restrict__ ti, _Float16* __restrict__ outp)
{
  const int tid = threadIdx.x;
  const int d4 = tid & 127;
  const int r  = (blockIdx.x << 1) + (tid >> 7);
  const int b  = r >> 12, l = r & 4095;
  const int h  = d4 >> 4;
  const float* w8 = tw + (((b << 3) + h) << 3);
  const int*   i8 = ti + (((b << 3) + h) << 3);
  f32x4_t acc = (f32x4_t){0.f, 0.f, 0.f, 0.f};
  #pragma unroll
  for (int k = 0; k < 8; ++k) {
    int ls = (l + i8[k]) & 4095;
    half4_t v = *(const half4_t*)(QKV + ((size_t)((b << 12) + ls)) * 1536 + 1024 + (d4 << 2));
    float wk = w8[k];
    acc[0] += (float)v[0] * wk; acc[1] += (float)v[1] * wk;
    acc[2] += (float)v[2] * wk; acc[3] += (float)v[3] * wk;
  }
  half4_t o;
  o[0] = (_Float16)acc[0]; o[1] = (_Float16)acc[1];
  o[2] = (_Float16)acc[2]; o[3] = (_Float16)acc[3];
  *(half4_t*)(outp + ((size_t)r << 9) + (d4 << 2)) = o;
}

// ---------------------------------------------------------------------------
// y(fp16) = LayerNorm(xa + xb) * g + be ; xa/xb dtype per template.
// ---------------------------------------------------------------------------
template<int XA16, int XB16>
__global__ __launch_bounds__(256) void ln_add16(
    const void* __restrict__ xa, const void* __restrict__ xb,
    const float* __restrict__ g, const float* __restrict__ be,
    _Float16* __restrict__ y)
{
  const int lane = threadIdx.x & 63;
  const int row  = (blockIdx.x << 2) + (threadIdx.x >> 6);
  const size_t base = ((size_t)row << 9) + (lane << 3);
  f32x4_t a0, a1, b0, b1;
  if (XA16) {
    half8_t v = *(const half8_t*)((const _Float16*)xa + base);
    a0[0]=(float)v[0]; a0[1]=(float)v[1]; a0[2]=(float)v[2]; a0[3]=(float)v[3];
    a1[0]=(float)v[4]; a1[1]=(float)v[5]; a1[2]=(float)v[6]; a1[3]=(float)v[7];
  } else {
    const float* ar = (const float*)xa + base;
    a0 = *(const f32x4_t*)ar; a1 = *(const f32x4_t*)(ar + 4);
  }
  if (XB16) {
    half8_t v = *(const half8_t*)((const _Float16*)xb + base);
    b0[0]=(float)v[0]; b0[1]=(float)v[1]; b0[2]=(float)v[2]; b0[3]=(float)v[3];
    b1[0]=(float)v[4]; b1[1]=(float)v[5]; b1[2]=(float)v[6]; b1[3]=(float)v[7];
  } else {
    const float* br = (const float*)xb + base;
    b0 = *(const f32x4_t*)br; b1 = *(const f32x4_t*)(br + 4);
  }
  f32x4_t v0 = a0 + b0, v1 = a1 + b1;
  float s  = v0[0] + v0[1] + v0[2] + v0[3] + v1[0] + v1[1] + v1[2] + v1[3];
  float s2 = v0[0]*v0[0] + v0[1]*v0[1] + v0[2]*v0[2] + v0[3]*v0[3]
           + v1[0]*v1[0] + v1[1]*v1[1] + v1[2]*v1[2] + v1[3]*v1[3];
  #pragma unroll
  for (int o = 1; o < 64; o <<= 1) { s += __shfl_xor(s, o); s2 += __shfl_xor(s2, o); }
  float mu  = s * (1.f / 512.f);
  float var = s2 * (1.f / 512.f) - mu * mu;
  float rs  = rsqrtf(var + 1e-5f);
  const float* gr  = g  + (lane << 3);
  const float* ber = be + (lane << 3);
  f32x4_t g0 = *(const f32x4_t*)gr,  g1v = *(const f32x4_t*)(gr + 4);
  f32x4_t e0 = *(const f32x4_t*)ber, e1  = *(const f32x4_t*)(ber + 4);
  half8_t o8;
  #pragma unroll
  for (int i = 0; i < 4; ++i) {
    o8[i]     = (_Float16)((v0[i] - mu) * rs * g0[i]  + e0[i]);
    o8[4 + i] = (_Float16)((v1[i] - mu) * rs * g1v[i] + e1[i]);
  }
  *(half8_t*)(y + base) = o8;
}

// ---------------------------------------------------------------------------
// Series decomposition from fp16 y: moving average window 25, edge-replicated.
// MODE 1: seasonal fp16 + trend fp32 (overwrite)
// MODE 2: seasonal fp32 (d_out) + trendOut += trend
// ---------------------------------------------------------------------------
template<int MODE>
__global__ __launch_bounds__(256) void movavg16(
    const _Float16* __restrict__ y, float* __restrict__ seasF,
    _Float16* __restrict__ seasH, float* __restrict__ trendOut)
{
  __shared__ float T[152 * 64];
  const int lt = blockIdx.x, dc = blockIdx.y, b = blockIdx.z;
  const int l0 = lt << 7, d0 = dc << 6;
  const int tid = threadIdx.x;
  for (int idx = tid; idx < 152 * 8; idx += 256) {
    int rr = idx >> 3, c8 = idx & 7;
    int ls = l0 - 12 + rr;
    ls = ls < 0 ? 0 : (ls > 4095 ? 4095 : ls);
    half8_t v = *(const half8_t*)(y + (((size_t)(b << 12) + ls) << 9) + d0 + (c8 << 3));
    float* tp = &T[rr * 64 + (c8 << 3)];
    f32x4_t lo, hi;
    lo[0]=(float)v[0]; lo[1]=(float)v[1]; lo[2]=(float)v[2]; lo[3]=(float)v[3];
    hi[0]=(float)v[4]; hi[1]=(float)v[5]; hi[2]=(float)v[6]; hi[3]=(float)v[7];
    *(f32x4_t*)tp = lo; *(f32x4_t*)(tp + 4) = hi;
  }
  __syncthreads();
  for (int idx = tid; idx < 128 * 16; idx += 256) {
    int rr = idx >> 4, c4 = idx & 15;
    f32x4_t s = (f32x4_t){0.f, 0.f, 0.f, 0.f};
    #pragma unroll
    for (int j = 0; j < 25; ++j) s += *(const f32x4_t*)&T[(rr + j) * 64 + (c4 << 2)];
    f32x4_t trend = s * (1.f / 25.f);
    f32x4_t ctr   = *(const f32x4_t*)&T[(rr + 12) * 64 + (c4 << 2)];
    f32x4_t seas  = ctr - trend;
    size_t gp = (((size_t)(b << 12) + l0 + rr) << 9) + d0 + (c4 << 2);
    if (MODE == 1) {
      half4_t sh;
      sh[0] = (_Float16)seas[0]; sh[1] = (_Float16)seas[1];
      sh[2] = (_Float16)seas[2]; sh[3] = (_Float16)seas[3];
      *(half4_t*)(seasH + gp) = sh;
      *(f32x4_t*)(trendOut + gp) = trend;
    } else {
      *(f32x4_t*)(seasF + gp) = seas;
      f32x4_t t1 = *(const f32x4_t*)(trendOut + gp);
      t1 += trend;
      *(f32x4_t*)(trendOut + gp) = t1;
    }
  }
}

// ---------------------------------------------------------------------------
// Prep (one dispatch): x fp32->fp16 convert + all weight transposes.
// Q/K/V transposed into ONE fused [1536][512] fp16 buffer.
// ---------------------------------------------------------------------------
__global__ __launch_bounds__(256) void prep_all(
    const float* __restrict__ x, _Float16* __restrict__ X16,
    const float* __restrict__ Wq, const float* __restrict__ Wk,
    const float* __restrict__ Wv, const float* __restrict__ Wo,
    const float* __restrict__ W1, const float* __restrict__ W2,
    _Float16* __restrict__ WQKVT, _Float16* __restrict__ WOT,
    _Float16* __restrict__ W1T, _Float16* __restrict__ W2T)
{
  const int bid = blockIdx.x;
  if (bid < 8192) {
    int i = bid * 256 + threadIdx.x;
    f32x4_t v = *(const f32x4_t*)(x + ((size_t)i << 2));
    half4_t o;
    o[0] = (_Float16)v[0]; o[1] = (_Float16)v[1];
    o[2] = (_Float16)v[2]; o[3] = (_Float16)v[3];
    *(half4_t*)(X16 + ((size_t)i << 2)) = o;
    return;
  }
  const int id = bid - 8192;
  const float* src; _Float16* dst; int Kd, Nd, kb, nb, nbase;
  if (id < 1024) {
    int wsel = id >> 8, r = id & 255;
    kb = (r & 15) << 5; nb = (r >> 4) << 5; Kd = 512; Nd = 512;
    src = wsel == 0 ? Wq : wsel == 1 ? Wk : wsel == 2 ? Wv : Wo;
    if (wsel < 3) { dst = WQKVT; nbase = (wsel << 9) + nb; }
    else          { dst = WOT;   nbase = nb; }
  } else if (id < 2048) {
    int r = id - 1024;
    kb = (r & 15) << 5; nb = (r >> 4) << 5; Kd = 512; Nd = 2048;
    src = W1; dst = W1T; nbase = nb;
  } else {
    int r = id - 2048;
    kb = (r & 63) << 5; nb = (r >> 6) << 5; Kd = 2048; Nd = 512;
    src = W2; dst = W2T; nbase = nb;
  }
  __shared__ float t[32][33];
  const int tx = threadIdx.x & 31, ty = threadIdx.x >> 5;
  #pragma unroll
  for (int r0 = 0; r0 < 32; r0 += 8)
    t[ty + r0][tx] = src[(size_t)(kb + ty + r0) * Nd + nb + tx];
  __syncthreads();
  #pragma unroll
  for (int r0 = 0; r0 < 32; r0 += 8)
    dst[(size_t)(nbase + ty + r0) * Kd + kb + tx] = (_Float16)t[tx][ty + r0];
}

// ---------------------------------------------------------------------------
extern "C" void kernel_launch(void* const* d_in, const int* in_sizes, int n_in,
                              void* d_out, int out_size, void* d_ws, size_t ws_size,
                              hipStream_t stream)
{
  const float* x   = (const float*)d_in[0];
  const float* Wq  = (const float*)d_in[1];
  const float* bq  = (const float*)d_in[2];
  const float* Wk  = (const float*)d_in[3];
  const float* bk  = (const float*)d_in[4];
  const float* Wv  = (const float*)d_in[5];
  const float* bv  = (const float*)d_in[6];
  const float* Wo  = (const float*)d_in[7];
  const float* bo  = (const float*)d_in[8];
  const float* W1  = (const float*)d_in[9];
  const float* b1  = (const float*)d_in[10];
  const float* W2  = (const float*)d_in[11];
  const float* b2  = (const float*)d_in[12];
  const float* g1  = (const float*)d_in[13];
  const float* be1 = (const float*)d_in[14];
  const float* g2  = (const float*)d_in[15];
  const float* be2 = (const float*)d_in[16];

  char* ws = (char*)d_ws;
  constexpr size_t ME = 16384ull * 512ull;                 // 8,388,608 elems
  constexpr size_t OFF_X16   = 0;                          // 16.78 MB fp16
  constexpr size_t OFF_WQKVT = OFF_X16 + 2 * ME;           // 1536x512 fp16
  constexpr size_t OFF_WOT   = OFF_WQKVT + 1536 * 512 * 2;
  constexpr size_t OFF_W1T   = OFF_WOT + 512 * 512 * 2;
  constexpr size_t OFF_W2T   = OFF_W1T + 2048 * 512 * 2;
  constexpr size_t OFF_QKV16 = OFF_W2T + 2048 * 512 * 2;   // 50.33 MB [16384][1536] fp16
  constexpr size_t OFF_ATTN16= OFF_QKV16 + 6 * ME;         // 16.78 MB fp16
  constexpr size_t OFF_FF16  = OFF_ATTN16 + 2 * ME;        // 16.78 MB fp16
  constexpr size_t OFF_CORRP = OFF_FF16 + 2 * ME;          // 0.52 MB
  constexpr size_t OFF_CORRN = OFF_CORRP + 32 * 4096 * 4;  // 0.52 MB
  constexpr size_t OFF_TW    = OFF_CORRN + 32 * 4096 * 4;
  constexpr size_t OFF_TI    = OFF_TW + 1024;
  // aliases (lifetime-disjoint reuse)
  constexpr size_t OFF_AIN16 = OFF_X16;    // gather out (X16 dead after QKV gemm)
  constexpr size_t OFF_S116  = OFF_X16;    // seasonal1 fp16 (AIN16 dead after O-proj)
  constexpr size_t OFF_Y116  = OFF_QKV16;  // QKV dead after gather
  constexpr size_t OFF_H16   = OFF_QKV16;  // 67.1 MB spans QKV16+ATTN16 (both dead pre-FFN1)
  constexpr size_t OFF_Y216  = OFF_QKV16;  // H16 dead after FFN2

  _Float16* X16   = (_Float16*)(ws + OFF_X16);
  _Float16* WQKVT = (_Float16*)(ws + OFF_WQKVT);
  _Float16* WOT   = (_Float16*)(ws + OFF_WOT);
  _Float16* W1T   = (_Float16*)(ws + OFF_W1T);
  _Float16* W2T   = (_Float16*)(ws + OFF_W2T);
  _Float16* QKV16 = (_Float16*)(ws + OFF_QKV16);
  _Float16* ATTN16= (_Float16*)(ws + OFF_ATTN16);
  _Float16* FF16  = (_Float16*)(ws + OFF_FF16);
  float*    CORRP = (float*)(ws + OFF_CORRP);
  float*    CORRN = (float*)(ws + OFF_CORRN);
  float*    TW    = (float*)(ws + OFF_TW);
  int*      TI    = (int*)(ws + OFF_TI);
  _Float16* AIN16 = (_Float16*)(ws + OFF_AIN16);
  _Float16* S116  = (_Float16*)(ws + OFF_S116);
  _Float16* H16   = (_Float16*)(ws + OFF_H16);
  _Float16* Y116  = (_Float16*)(ws + OFF_Y116);
  _Float16* Y216  = (_Float16*)(ws + OFF_Y216);

  float* OUT_SEAS  = (float*)d_out;            // seasonal2
  float* OUT_TREND = (float*)d_out + ME;       // trend1 + trend2

  // --- prep (convert + transposes, one dispatch) ---
  prep_all<<<11264, 256, 0, stream>>>(x, X16, Wq, Wk, Wv, Wo, W1, W2,
                                      WQKVT, WOT, W1T, W2T);

  // --- fused QKV projection: [16384,1536] = X16 @ WQKVT^T ---
  gemm_f16k<true, false><<<dim3(128, 12), 256, 0, stream>>>(
      X16, WQKVT, bq, bk, bv, 9, QKV16, 16384, 1536, 512);

  // --- autocorrelation ---
  corr_gram6<<<2048, 256, 0, stream>>>(QKV16, CORRP, CORRN);
  topk_softmax<<<32, 256, 0, stream>>>(CORRP, CORRN, TW, TI);
  gather_attn<<<8192, 256, 0, stream>>>(QKV16, TW, TI, AIN16);
  gemm_f16k<true, false><<<dim3(128, 4), 256, 0, stream>>>(
      AIN16, WOT, bo, bo, bo, 31, ATTN16, 16384, 512, 512);

  // --- LN1 + decomp1 ---
  ln_add16<0, 1><<<4096, 256, 0, stream>>>(x, ATTN16, g1, be1, Y116);
  movavg16<1><<<dim3(32, 8, 4), 256, 0, stream>>>(Y116, nullptr, S116, OUT_TREND);

  // --- FFN ---
  gemm_f16k<true, true ><<<dim3(128, 16), 256, 0, stream>>>(
      S116, W1T, b1, b1, b1, 31, H16, 16384, 2048, 512);
  gemm_f16k<true, false><<<dim3(128, 4), 256, 0, stream>>>(
      H16, W2T, b2, b2, b2, 31, FF16, 16384, 512, 2048);

  // --- LN2 + decomp2 ---
  ln_add16<1, 1><<<4096, 256, 0, stream>>>(S116, FF16, g2, be2, Y216);
  movavg16<2><<<dim3(32, 8, 4), 256, 0, stream>>>(Y216, OUT_SEAS, nullptr, OUT_TREND);
}

// Round 8
// 489.511 us; speedup vs baseline: 1.0566x; 1.0566x over previous
//
#include <hip/hip_runtime.h>
#include <hip/hip_bf16.h>
#include <math.h>

// ---------------------------------------------------------------------------
// Autoformer encoder layer, MI355X (gfx950).
// B=4, L=4096, D=512, H=8, dk=64, F=2048, MA=25, top_k=8.
// GEMMs in fp16 MFMA (16x16x32_f16), fp32 accumulate; fp16 intermediates.
// ---------------------------------------------------------------------------

typedef _Float16 half8_t __attribute__((ext_vector_type(8)));
typedef _Float16 half4_t __attribute__((ext_vector_type(4)));
typedef float    f32x4_t __attribute__((ext_vector_type(4)));

__device__ __forceinline__ void gl_lds16(const _Float16* src, _Float16* dst) {
  __builtin_amdgcn_global_load_lds(
      (const __attribute__((address_space(1))) unsigned int*)(const void*)src,
      (__attribute__((address_space(3))) unsigned int*)(void*)dst, 16, 0, 0);
}

// ---------------------------------------------------------------------------
// Generic fp16 GEMM:  out[M,N] = A[M,K] @ Bt[N,K]^T + bias, optional GELU.
// 128x128 tile, BK=64, 256 threads (4 waves, 2x2), XOR-swizzled LDS.
// Swapped-operand epilogue (N on reg axis -> vector stores).
// ---------------------------------------------------------------------------
template<bool OUT16, bool DOGELU>
__global__ __launch_bounds__(256) void gemm_f16k(
    const _Float16* __restrict__ A, const _Float16* __restrict__ Bt,
    const float* __restrict__ bs0, const float* __restrict__ bs1,
    const float* __restrict__ bs2, int segShift,
    void* __restrict__ outp, int M, int N, int K)
{
  __shared__ _Float16 As[128 * 64];
  __shared__ _Float16 Bs[128 * 64];
  const int tid = threadIdx.x, lane = tid & 63, w = tid >> 6;
  const int wr = w >> 1, wc = w & 1;
  const int m0 = blockIdx.x * 128, n0 = blockIdx.y * 128;

  f32x4_t acc[4][4];
  #pragma unroll
  for (int i = 0; i < 4; ++i)
    #pragma unroll
    for (int j = 0; j < 4; ++j) acc[i][j] = (f32x4_t){0.f, 0.f, 0.f, 0.f};

  const _Float16* Ab = A + (size_t)m0 * K;
  const _Float16* Bb = Bt + (size_t)n0 * K;

  for (int k0 = 0; k0 < K; k0 += 64) {
    #pragma unroll
    for (int q = 0; q < 4; ++q) {
      int off = ((w << 2) + q) << 10;
      int row = (off >> 7) + (lane >> 3);
      int sl  = (lane & 7) ^ (row & 7);
      gl_lds16(Ab + (size_t)row * K + k0 + (sl << 3), As + (off >> 1));
    }
    #pragma unroll
    for (int q = 0; q < 4; ++q) {
      int off = ((w << 2) + q) << 10;
      int row = (off >> 7) + (lane >> 3);
      int sl  = (lane & 7) ^ (row & 7);
      gl_lds16(Bb + (size_t)row * K + k0 + (sl << 3), Bs + (off >> 1));
    }
    __syncthreads();

    #pragma unroll
    for (int kk = 0; kk < 2; ++kk) {
      half8_t af[4], bf[4];
      #pragma unroll
      for (int mi = 0; mi < 4; ++mi) {
        int row = wr * 64 + mi * 16 + (lane & 15);
        int sl  = ((kk << 2) + (lane >> 4)) ^ (row & 7);
        af[mi] = *(const half8_t*)(As + row * 64 + (sl << 3));
      }
      #pragma unroll
      for (int ni = 0; ni < 4; ++ni) {
        int row = wc * 64 + ni * 16 + (lane & 15);
        int sl  = ((kk << 2) + (lane >> 4)) ^ (row & 7);
        bf[ni] = *(const half8_t*)(Bs + row * 64 + (sl << 3));
      }
      #pragma unroll
      for (int mi = 0; mi < 4; ++mi)
        #pragma unroll
        for (int ni = 0; ni < 4; ++ni)
          acc[mi][ni] = __builtin_amdgcn_mfma_f32_16x16x32_f16(
              bf[ni], af[mi], acc[mi][ni], 0, 0, 0);   // swapped: N on reg axis
    }
    __syncthreads();
  }

  int seg = n0 >> segShift; if (seg > 2) seg = 2;
  const float* bias = seg == 0 ? bs0 : (seg == 1 ? bs1 : bs2);
  const unsigned bmask = (segShift >= 31) ? 0xffffffffu : ((1u << segShift) - 1u);

  #pragma unroll
  for (int ni = 0; ni < 4; ++ni) {
    int n = n0 + wc * 64 + ni * 16 + ((lane >> 4) << 2);
    f32x4_t b4 = *(const f32x4_t*)(bias + (n & bmask));
    #pragma unroll
    for (int mi = 0; mi < 4; ++mi) {
      int m = m0 + wr * 64 + mi * 16 + (lane & 15);
      f32x4_t v = acc[mi][ni] + b4;
      if (DOGELU) {
        #pragma unroll
        for (int r = 0; r < 4; ++r)
          v[r] = 0.5f * v[r] * (1.f + erff(v[r] * 0.70710678118654752f));
      }
      if (OUT16) {
        half4_t o;
        o[0] = (_Float16)v[0]; o[1] = (_Float16)v[1];
        o[2] = (_Float16)v[2]; o[3] = (_Float16)v[3];
        *(half4_t*)((_Float16*)outp + (size_t)m * N + n) = o;
      } else {
        *(f32x4_t*)((float*)outp + (size_t)m * N + n) = v;
      }
    }
  }
}

// ---------------------------------------------------------------------------
// Autocorrelation v7: block owns (b, h, tau-window [64T, 64T+64)).
// 64x64x4096 band GEMM, register-accumulated. Double-buffered tile pairs
// (34.8KB LDS -> 4 blocks/CU) like v5, but per J only ONE wave-pair computes
// (waves 0,1 <-> even J; waves 2,3 <-> odd J), each wave a k-half (32 elems
// = one 16x16x32 MFMA K). Each staged tile read exactly once: 32KB LDS/J
// (-33% vs v5) while staging stays overlapped with compute.
// Epilogue: 4 waves hold {parity}x{k-half} partials -> serial Gd accumulate,
// then verified diagonal extraction. No atomics.
// ---------------------------------------------------------------------------
__global__ __launch_bounds__(256) void corr_gram7(
    const _Float16* __restrict__ QKV,
    float* __restrict__ corrP, float* __restrict__ corrN)
{
  __shared__ __attribute__((aligned(16))) char smem[34816];
  _Float16* tiles = (_Float16*)smem;   // buf p: Q at p*8192, K at p*8192+4096
  float*    Gd    = (float*)smem;      // [128][68] after loop

  const int tid = threadIdx.x, lane = tid & 63, w = tid >> 6;
  const int p  = blockIdx.x;
  const int lg = ((p & 7) << 8) + (p >> 3);   // XCD-chunked swizzle
  const int T = lg & 63, h = (lg >> 6) & 7, b = lg >> 9;
  const int myPar = w >> 1, kh = w & 1;

  // ---- hoisted staging offsets: 4 issues/wave (u = w*4+q; tsel=u>>3; v=u&7)
  size_t goff[4]; int loff[4]; int tsel[4];
  #pragma unroll
  for (int q = 0; q < 4; ++q) {
    int u = (w << 2) + q;
    tsel[q] = u >> 3;                    // 0 = Q tile, 1 = K tile
    int v = u & 7;
    int row = (v << 3) + (lane >> 3);
    int sl  = (lane & 7) ^ (row & 7);
    goff[q] = (size_t)row * 1536 + (sl << 3) + h * 64 + (tsel[q] ? 512 : 0);
    loff[q] = tsel[q] * 4096 + v * 512 + (lane << 3);
  }
  const size_t bbase = (size_t)b * 4096 * 1536;

  // ---- hoisted frag offsets (k-half kh; identical formula for Q and K)
  int foff[4];
  #pragma unroll
  for (int mi = 0; mi < 4; ++mi) {
    int row = (mi << 4) + (lane & 15);
    int sl  = ((kh << 2) + (lane >> 4)) ^ (row & 7);
    foff[mi] = row * 64 + (sl << 3);
  }

  f32x4_t acc[4][4];
  #pragma unroll
  for (int i = 0; i < 4; ++i)
    #pragma unroll
    for (int j = 0; j < 4; ++j) acc[i][j] = (f32x4_t){0.f, 0.f, 0.f, 0.f};

  auto stage = [&](int buf, int J) {
    const size_t qb = bbase + (size_t)((T + J) & 63) * 98304;
    const size_t kb = bbase + (size_t)J * 98304;
    _Float16* dst = tiles + buf * 8192;
    #pragma unroll
    for (int q = 0; q < 4; ++q)
      gl_lds16(QKV + (tsel[q] ? kb : qb) + goff[q], dst + loff[q]);
  };

  stage(0, 0);
  __syncthreads();                       // buf0 ready (vmcnt drained)

  for (int J = 0; J < 64; ++J) {
    const int par = J & 1;
    if (J < 63) stage(par ^ 1, J + 1);   // async, overlaps compute
    if (myPar == par) {
      const _Float16* Qb = tiles + par * 8192;
      const _Float16* Kb = Qb + 4096;
      half8_t af[4], bf[4];
      #pragma unroll
      for (int mi = 0; mi < 4; ++mi) af[mi] = *(const half8_t*)(Qb + foff[mi]);
      #pragma unroll
      for (int ni = 0; ni < 4; ++ni) bf[ni] = *(const half8_t*)(Kb + foff[ni]);
      #pragma unroll
      for (int mi = 0; mi < 4; ++mi)
        #pragma unroll
        for (int ni = 0; ni < 4; ++ni)
          acc[mi][ni] = __builtin_amdgcn_mfma_f32_16x16x32_f16(
              af[mi], bf[ni], acc[mi][ni], 0, 0, 0);
    }
    __syncthreads();                     // reads done; next tiles landed
  }

  // ---- diagonal accumulation: Gd zero, then waves add serially
  for (int idx = tid; idx < 128 * 68; idx += 256) Gd[idx] = 0.f;
  __syncthreads();
  #pragma unroll 1
  for (int wv = 0; wv < 4; ++wv) {
    if (w == wv) {
      #pragma unroll
      for (int mi = 0; mi < 4; ++mi)
        #pragma unroll
        for (int ni = 0; ni < 4; ++ni)
          #pragma unroll
          for (int r = 0; r < 4; ++r) {
            int row = (mi << 4) + ((lane >> 4) << 2) + r;
            int col = (ni << 4) + (lane & 15);
            Gd[(row - col + 64) * 68 + col] += acc[mi][ni][r];
          }
    }
    __syncthreads();
  }

  float s;
  {
    const float* gp = &Gd[(tid >> 1) * 68 + ((tid & 1) << 5)];
    f32x4_t x0 = *(const f32x4_t*)gp        + *(const f32x4_t*)(gp + 4);
    f32x4_t x1 = *(const f32x4_t*)(gp + 8)  + *(const f32x4_t*)(gp + 12);
    f32x4_t x2 = *(const f32x4_t*)(gp + 16) + *(const f32x4_t*)(gp + 20);
    f32x4_t x3 = *(const f32x4_t*)(gp + 24) + *(const f32x4_t*)(gp + 28);
    x0 += x1; x2 += x3; x0 += x2;
    s = x0[0] + x0[1] + x0[2] + x0[3];
  }
  s += __shfl_xor(s, 1);
  if ((tid & 1) == 0) {
    const size_t bh = (size_t)(b * 8 + h) << 12;
    int v = tid >> 1;
    if (v == 0) {
      corrN[bh + (T << 6)] = 0.f;          // tau==0 mod 64: no negative part
    } else {
      int d = v - 64;
      int tau = ((T << 6) + d) & 4095;
      if (d >= 0) corrP[bh + tau] = s;
      else        corrN[bh + tau] = s;
    }
  }
}

// ---------------------------------------------------------------------------
// Top-8 + softmax per (b,h). corr = corrP + corrN. Lowest-index tie-break.
// ---------------------------------------------------------------------------
__global__ __launch_bounds__(256) void topk_softmax(
    const float* __restrict__ corrP, const float* __restrict__ corrN,
    float* __restrict__ tw, int* __restrict__ ti)
{
  __shared__ float vals[4096];
  __shared__ float wvv[4]; __shared__ int wii[4];
  __shared__ float rv[8]; __shared__ int ri[8];
  const int tid = threadIdx.x;
  const int bh = blockIdx.x;
  const float* cp = corrP + (size_t)bh * 4096;
  const float* cn = corrN + (size_t)bh * 4096;
  for (int i = tid; i < 4096; i += 256) vals[i] = cp[i] + cn[i];
  __syncthreads();

  for (int it = 0; it < 8; ++it) {
    float bv = -3.4e38f; int bi = 1 << 30;
    for (int i = tid; i < 4096; i += 256) {
      float v = vals[i];
      if (v > bv) { bv = v; bi = i; }
    }
    #pragma unroll
    for (int o = 32; o > 0; o >>= 1) {
      float ov = __shfl_down(bv, o);
      int   oi = __shfl_down(bi, o);
      if (ov > bv || (ov == bv && oi < bi)) { bv = ov; bi = oi; }
    }
    if ((tid & 63) == 0) { wvv[tid >> 6] = bv; wii[tid >> 6] = bi; }
    __syncthreads();
    if (tid == 0) {
      for (int k = 1; k < 4; ++k)
        if (wvv[k] > bv || (wvv[k] == bv && wii[k] < bi)) { bv = wvv[k]; bi = wii[k]; }
      rv[it] = bv; ri[it] = bi; vals[bi] = -3.4e38f;
    }
    __syncthreads();
  }

  if (tid == 0) {
    float m = rv[0] * (1.f / 64.f);          // corr_mean = corr/dk; rv[0] is max
    float e[8]; float s = 0.f;
    for (int k = 0; k < 8; ++k) { e[k] = expf(rv[k] * (1.f / 64.f) - m); s += e[k]; }
    float inv = 1.f / s;
    for (int k = 0; k < 8; ++k) { tw[bh * 8 + k] = e[k] * inv; ti[bh * 8 + k] = ri[k]; }
  }
}

// ---------------------------------------------------------------------------
// out[b,l,h*64+d] = sum_k tw[k] * V[b,(l+ti[k])%L, h*64+d]; V inside QKV
// (stride 1536, col offset 1024). Output fp16 [16384][512].
// ---------------------------------------------------------------------------
__global__ __launch_bounds__(256) void gather_attn(
    const _Float16* __restrict__ QKV, const float* __restrict__ tw,
    const int* __restrict__ ti, _Float16* __restrict__ outp)
{
  const int tid = threadIdx.x;
  const int d4 = tid & 127;
  const int r  = (blockIdx.x << 1) + (tid >> 7);
  const int b  = r >> 12, l = r & 4095;
  const int h  = d4 >> 4;
  const float* w8 = tw + (((b << 3) + h) << 3);
  const int*   i8 = ti + (((b << 3) + h) << 3);
  f32x4_t acc = (f32x4_t){0.f, 0.f, 0.f, 0.f};
  #pragma unroll
  for (int k = 0; k < 8; ++k) {
    int ls = (l + i8[k]) & 4095;
    half4_t v = *(const half4_t*)(QKV + ((size_t)((b << 12) + ls)) * 1536 + 1024 + (d4 << 2));
    float wk = w8[k];
    acc[0] += (float)v[0] * wk; acc[1] += (float)v[1] * wk;
    acc[2] += (float)v[2] * wk; acc[3] += (float)v[3] * wk;
  }
  half4_t o;
  o[0] = (_Float16)acc[0]; o[1] = (_Float16)acc[1];
  o[2] = (_Float16)acc[2]; o[3] = (_Float16)acc[3];
  *(half4_t*)(outp + ((size_t)r << 9) + (d4 << 2)) = o;
}

// ---------------------------------------------------------------------------
// y(fp16) = LayerNorm(xa + xb) * g + be ; xa/xb dtype per template.
// ---------------------------------------------------------------------------
template<int XA16, int XB16>
__global__ __launch_bounds__(256) void ln_add16(
    const void* __restrict__ xa, const void* __restrict__ xb,
    const float* __restrict__ g, const float* __restrict__ be,
    _Float16* __restrict__ y)
{
  const int lane = threadIdx.x & 63;
  const int row  = (blockIdx.x << 2) + (threadIdx.x >> 6);
  const size_t base = ((size_t)row << 9) + (lane << 3);
  f32x4_t a0, a1, b0, b1;
  if (XA16) {
    half8_t v = *(const half8_t*)((const _Float16*)xa + base);
    a0[0]=(float)v[0]; a0[1]=(float)v[1]; a0[2]=(float)v[2]; a0[3]=(float)v[3];
    a1[0]=(float)v[4]; a1[1]=(float)v[5]; a1[2]=(float)v[6]; a1[3]=(float)v[7];
  } else {
    const float* ar = (const float*)xa + base;
    a0 = *(const f32x4_t*)ar; a1 = *(const f32x4_t*)(ar + 4);
  }
  if (XB16) {
    half8_t v = *(const half8_t*)((const _Float16*)xb + base);
    b0[0]=(float)v[0]; b0[1]=(float)v[1]; b0[2]=(float)v[2]; b0[3]=(float)v[3];
    b1[0]=(float)v[4]; b1[1]=(float)v[5]; b1[2]=(float)v[6]; b1[3]=(float)v[7];
  } else {
    const float* br = (const float*)xb + base;
    b0 = *(const f32x4_t*)br; b1 = *(const f32x4_t*)(br + 4);
  }
  f32x4_t v0 = a0 + b0, v1 = a1 + b1;
  float s  = v0[0] + v0[1] + v0[2] + v0[3] + v1[0] + v1[1] + v1[2] + v1[3];
  float s2 = v0[0]*v0[0] + v0[1]*v0[1] + v0[2]*v0[2] + v0[3]*v0[3]
           + v1[0]*v1[0] + v1[1]*v1[1] + v1[2]*v1[2] + v1[3]*v1[3];
  #pragma unroll
  for (int o = 1; o < 64; o <<= 1) { s += __shfl_xor(s, o); s2 += __shfl_xor(s2, o); }
  float mu  = s * (1.f / 512.f);
  float var = s2 * (1.f / 512.f) - mu * mu;
  float rs  = rsqrtf(var + 1e-5f);
  const float* gr  = g  + (lane << 3);
  const float* ber = be + (lane << 3);
  f32x4_t g0 = *(const f32x4_t*)gr,  g1v = *(const f32x4_t*)(gr + 4);
  f32x4_t e0 = *(const f32x4_t*)ber, e1  = *(const f32x4_t*)(ber + 4);
  half8_t o8;
  #pragma unroll
  for (int i = 0; i < 4; ++i) {
    o8[i]     = (_Float16)((v0[i] - mu) * rs * g0[i]  + e0[i]);
    o8[4 + i] = (_Float16)((v1[i] - mu) * rs * g1v[i] + e1[i]);
  }
  *(half8_t*)(y + base) = o8;
}

// ---------------------------------------------------------------------------
// Series decomposition from fp16 y: moving average window 25, edge-replicated.
// MODE 1: seasonal fp16 + trend fp32 (overwrite)
// MODE 2: seasonal fp32 (d_out) + trendOut += trend
// ---------------------------------------------------------------------------
template<int MODE>
__global__ __launch_bounds__(256) void movavg16(
    const _Float16* __restrict__ y, float* __restrict__ seasF,
    _Float16* __restrict__ seasH, float* __restrict__ trendOut)
{
  __shared__ float T[152 * 64];
  const int lt = blockIdx.x, dc = blockIdx.y, b = blockIdx.z;
  const int l0 = lt << 7, d0 = dc << 6;
  const int tid = threadIdx.x;
  for (int idx = tid; idx < 152 * 8; idx += 256) {
    int rr = idx >> 3, c8 = idx & 7;
    int ls = l0 - 12 + rr;
    ls = ls < 0 ? 0 : (ls > 4095 ? 4095 : ls);
    half8_t v = *(const half8_t*)(y + (((size_t)(b << 12) + ls) << 9) + d0 + (c8 << 3));
    float* tp = &T[rr * 64 + (c8 << 3)];
    f32x4_t lo, hi;
    lo[0]=(float)v[0]; lo[1]=(float)v[1]; lo[2]=(float)v[2]; lo[3]=(float)v[3];
    hi[0]=(float)v[4]; hi[1]=(float)v[5]; hi[2]=(float)v[6]; hi[3]=(float)v[7];
    *(f32x4_t*)tp = lo; *(f32x4_t*)(tp + 4) = hi;
  }
  __syncthreads();
  for (int idx = tid; idx < 128 * 16; idx += 256) {
    int rr = idx >> 4, c4 = idx & 15;
    f32x4_t s = (f32x4_t){0.f, 0.f, 0.f, 0.f};
    #pragma unroll
    for (int j = 0; j < 25; ++j) s += *(const f32x4_t*)&T[(rr + j) * 64 + (c4 << 2)];
    f32x4_t trend = s * (1.f / 25.f);
    f32x4_t ctr   = *(const f32x4_t*)&T[(rr + 12) * 64 + (c4 << 2)];
    f32x4_t seas  = ctr - trend;
    size_t gp = (((size_t)(b << 12) + l0 + rr) << 9) + d0 + (c4 << 2);
    if (MODE == 1) {
      half4_t sh;
      sh[0] = (_Float16)seas[0]; sh[1] = (_Float16)seas[1];
      sh[2] = (_Float16)seas[2]; sh[3] = (_Float16)seas[3];
      *(half4_t*)(seasH + gp) = sh;
      *(f32x4_t*)(trendOut + gp) = trend;
    } else {
      *(f32x4_t*)(seasF + gp) = seas;
      f32x4_t t1 = *(const f32x4_t*)(trendOut + gp);
      t1 += trend;
      *(f32x4_t*)(trendOut + gp) = t1;
    }
  }
}

// ---------------------------------------------------------------------------
// Prep (one dispatch): x fp32->fp16 convert + all weight transposes.
// Q/K/V transposed into ONE fused [1536][512] fp16 buffer.
// ---------------------------------------------------------------------------
__global__ __launch_bounds__(256) void prep_all(
    const float* __restrict__ x, _Float16* __restrict__ X16,
    const float* __restrict__ Wq, const float* __restrict__ Wk,
    const float* __restrict__ Wv, const float* __restrict__ Wo,
    const float* __restrict__ W1, const float* __restrict__ W2,
    _Float16* __restrict__ WQKVT, _Float16* __restrict__ WOT,
    _Float16* __restrict__ W1T, _Float16* __restrict__ W2T)
{
  const int bid = blockIdx.x;
  if (bid < 8192) {
    int i = bid * 256 + threadIdx.x;
    f32x4_t v = *(const f32x4_t*)(x + ((size_t)i << 2));
    half4_t o;
    o[0] = (_Float16)v[0]; o[1] = (_Float16)v[1];
    o[2] = (_Float16)v[2]; o[3] = (_Float16)v[3];
    *(half4_t*)(X16 + ((size_t)i << 2)) = o;
    return;
  }
  const int id = bid - 8192;
  const float* src; _Float16* dst; int Kd, Nd, kb, nb, nbase;
  if (id < 1024) {
    int wsel = id >> 8, r = id & 255;
    kb = (r & 15) << 5; nb = (r >> 4) << 5; Kd = 512; Nd = 512;
    src = wsel == 0 ? Wq : wsel == 1 ? Wk : wsel == 2 ? Wv : Wo;
    if (wsel < 3) { dst = WQKVT; nbase = (wsel << 9) + nb; }
    else          { dst = WOT;   nbase = nb; }
  } else if (id < 2048) {
    int r = id - 1024;
    kb = (r & 15) << 5; nb = (r >> 4) << 5; Kd = 512; Nd = 2048;
    src = W1; dst = W1T; nbase = nb;
  } else {
    int r = id - 2048;
    kb = (r & 63) << 5; nb = (r >> 6) << 5; Kd = 2048; Nd = 512;
    src = W2; dst = W2T; nbase = nb;
  }
  __shared__ float t[32][33];
  const int tx = threadIdx.x & 31, ty = threadIdx.x >> 5;
  #pragma unroll
  for (int r0 = 0; r0 < 32; r0 += 8)
    t[ty + r0][tx] = src[(size_t)(kb + ty + r0) * Nd + nb + tx];
  __syncthreads();
  #pragma unroll
  for (int r0 = 0; r0 < 32; r0 += 8)
    dst[(size_t)(nbase + ty + r0) * Kd + kb + tx] = (_Float16)t[tx][ty + r0];
}

// ---------------------------------------------------------------------------
extern "C" void kernel_launch(void* const* d_in, const int* in_sizes, int n_in,
                              void* d_out, int out_size, void* d_ws, size_t ws_size,
                              hipStream_t stream)
{
  const float* x   = (const float*)d_in[0];
  const float* Wq  = (const float*)d_in[1];
  const float* bq  = (const float*)d_in[2];
  const float* Wk  = (const float*)d_in[3];
  const float* bk  = (const float*)d_in[4];
  const float* Wv  = (const float*)d_in[5];
  const float* bv  = (const float*)d_in[6];
  const float* Wo  = (const float*)d_in[7];
  const float* bo  = (const float*)d_in[8];
  const float* W1  = (const float*)d_in[9];
  const float* b1  = (const float*)d_in[10];
  const float* W2  = (const float*)d_in[11];
  const float* b2  = (const float*)d_in[12];
  const float* g1  = (const float*)d_in[13];
  const float* be1 = (const float*)d_in[14];
  const float* g2  = (const float*)d_in[15];
  const float* be2 = (const float*)d_in[16];

  char* ws = (char*)d_ws;
  constexpr size_t ME = 16384ull * 512ull;                 // 8,388,608 elems
  constexpr size_t OFF_X16   = 0;                          // 16.78 MB fp16
  constexpr size_t OFF_WQKVT = OFF_X16 + 2 * ME;           // 1536x512 fp16
  constexpr size_t OFF_WOT   = OFF_WQKVT + 1536 * 512 * 2;
  constexpr size_t OFF_W1T   = OFF_WOT + 512 * 512 * 2;
  constexpr size_t OFF_W2T   = OFF_W1T + 2048 * 512 * 2;
  constexpr size_t OFF_QKV16 = OFF_W2T + 2048 * 512 * 2;   // 50.33 MB [16384][1536] fp16
  constexpr size_t OFF_ATTN16= OFF_QKV16 + 6 * ME;         // 16.78 MB fp16
  constexpr size_t OFF_FF16  = OFF_ATTN16 + 2 * ME;        // 16.78 MB fp16
  constexpr size_t OFF_CORRP = OFF_FF16 + 2 * ME;          // 0.52 MB
  constexpr size_t OFF_CORRN = OFF_CORRP + 32 * 4096 * 4;  // 0.52 MB
  constexpr size_t OFF_TW    = OFF_CORRN + 32 * 4096 * 4;
  constexpr size_t OFF_TI    = OFF_TW + 1024;
  // aliases (lifetime-disjoint reuse)
  constexpr size_t OFF_AIN16 = OFF_X16;    // gather out (X16 dead after QKV gemm)
  constexpr size_t OFF_S116  = OFF_X16;    // seasonal1 fp16 (AIN16 dead after O-proj)
  constexpr size_t OFF_Y116  = OFF_QKV16;  // QKV dead after gather
  constexpr size_t OFF_H16   = OFF_QKV16;  // 67.1 MB spans QKV16+ATTN16 (both dead pre-FFN1)
  constexpr size_t OFF_Y216  = OFF_QKV16;  // H16 dead after FFN2

  _Float16* X16   = (_Float16*)(ws + OFF_X16);
  _Float16* WQKVT = (_Float16*)(ws + OFF_WQKVT);
  _Float16* WOT   = (_Float16*)(ws + OFF_WOT);
  _Float16* W1T   = (_Float16*)(ws + OFF_W1T);
  _Float16* W2T   = (_Float16*)(ws + OFF_W2T);
  _Float16* QKV16 = (_Float16*)(ws + OFF_QKV16);
  _Float16* ATTN16= (_Float16*)(ws + OFF_ATTN16);
  _Float16* FF16  = (_Float16*)(ws + OFF_FF16);
  float*    CORRP = (float*)(ws + OFF_CORRP);
  float*    CORRN = (float*)(ws + OFF_CORRN);
  float*    TW    = (float*)(ws + OFF_TW);
  int*      TI    = (int*)(ws + OFF_TI);
  _Float16* AIN16 = (_Float16*)(ws + OFF_AIN16);
  _Float16* S116  = (_Float16*)(ws + OFF_S116);
  _Float16* H16   = (_Float16*)(ws + OFF_H16);
  _Float16* Y116  = (_Float16*)(ws + OFF_Y116);
  _Float16* Y216  = (_Float16*)(ws + OFF_Y216);

  float* OUT_SEAS  = (float*)d_out;            // seasonal2
  float* OUT_TREND = (float*)d_out + ME;       // trend1 + trend2

  // --- prep (convert + transposes, one dispatch) ---
  prep_all<<<11264, 256, 0, stream>>>(x, X16, Wq, Wk, Wv, Wo, W1, W2,
                                      WQKVT, WOT, W1T, W2T);

  // --- fused QKV projection: [16384,1536] = X16 @ WQKVT^T ---
  gemm_f16k<true, false><<<dim3(128, 12), 256, 0, stream>>>(
      X16, WQKVT, bq, bk, bv, 9, QKV16, 16384, 1536, 512);

  // --- autocorrelation ---
  corr_gram7<<<2048, 256, 0, stream>>>(QKV16, CORRP, CORRN);
  topk_softmax<<<32, 256, 0, stream>>>(CORRP, CORRN, TW, TI);
  gather_attn<<<8192, 256, 0, stream>>>(QKV16, TW, TI, AIN16);
  gemm_f16k<true, false><<<dim3(128, 4), 256, 0, stream>>>(
      AIN16, WOT, bo, bo, bo, 31, ATTN16, 16384, 512, 512);

  // --- LN1 + decomp1 ---
  ln_add16<0, 1><<<4096, 256, 0, stream>>>(x, ATTN16, g1, be1, Y116);
  movavg16<1><<<dim3(32, 8, 4), 256, 0, stream>>>(Y116, nullptr, S116, OUT_TREND);

  // --- FFN ---
  gemm_f16k<true, true ><<<dim3(128, 16), 256, 0, stream>>>(
      S116, W1T, b1, b1, b1, 31, H16, 16384, 2048, 512);
  gemm_f16k<true, false><<<dim3(128, 4), 256, 0, stream>>>(
      H16, W2T, b2, b2, b2, 31, FF16, 16384, 512, 2048);

  // --- LN2 + decomp2 ---
  ln_add16<1, 1><<<4096, 256, 0, stream>>>(S116, FF16, g2, be2, Y216);
  movavg16<2><<<dim3(32, 8, 4), 256, 0, stream>>>(Y216, OUT_SEAS, nullptr, OUT_TREND);
}

// Round 10
// 480.746 us; speedup vs baseline: 1.0758x; 1.0182x over previous
//
#include <hip/hip_runtime.h>
#include <hip/hip_bf16.h>
#include <math.h>

// ---------------------------------------------------------------------------
// Autoformer encoder layer, MI355X (gfx950).
// B=4, L=4096, D=512, H=8, dk=64, F=2048, MA=25, top_k=8.
// GEMMs in fp16 MFMA (16x16x32_f16), fp32 accumulate; fp16 intermediates.
// ---------------------------------------------------------------------------

typedef _Float16 half8_t __attribute__((ext_vector_type(8)));
typedef _Float16 half4_t __attribute__((ext_vector_type(4)));
typedef float    f32x4_t __attribute__((ext_vector_type(4)));

__device__ __forceinline__ void gl_lds16(const _Float16* src, _Float16* dst) {
  __builtin_amdgcn_global_load_lds(
      (const __attribute__((address_space(1))) unsigned int*)(const void*)src,
      (__attribute__((address_space(3))) unsigned int*)(void*)dst, 16, 0, 0);
}

// ---------------------------------------------------------------------------
// Generic fp16 GEMM:  out[M,N] = A[M,K] @ Bt[N,K]^T + bias, optional GELU.
// 128x128 tile, BK=64, 256 threads (4 waves, 2x2), XOR-swizzled LDS.
// Linear grid + bijective XCD-chunk swizzle, N-fast decomposition: each XCD
// owns a contiguous M-stripe (all N blocks) -> every A-panel fetched from
// HBM exactly once into exactly one XCD L2. Requires gridDim.x % 8 == 0.
// Swapped-operand epilogue (N on reg axis -> vector stores).
// ---------------------------------------------------------------------------
template<bool OUT16, bool DOGELU>
__global__ __launch_bounds__(256) void gemm_f16k(
    const _Float16* __restrict__ A, const _Float16* __restrict__ Bt,
    const float* __restrict__ bs0, const float* __restrict__ bs1,
    const float* __restrict__ bs2, int segShift,
    void* __restrict__ outp, int M, int N, int K, int nbx)
{
  __shared__ _Float16 As[128 * 64];
  __shared__ _Float16 Bs[128 * 64];
  const int tid = threadIdx.x, lane = tid & 63, w = tid >> 6;
  const int wr = w >> 1, wc = w & 1;
  const int cpx = gridDim.x >> 3;
  const int bid = blockIdx.x;
  const int idx = (bid & 7) * cpx + (bid >> 3);   // XCD-chunked
  const int m0 = (idx / nbx) * 128, n0 = (idx % nbx) * 128;

  f32x4_t acc[4][4];
  #pragma unroll
  for (int i = 0; i < 4; ++i)
    #pragma unroll
    for (int j = 0; j < 4; ++j) acc[i][j] = (f32x4_t){0.f, 0.f, 0.f, 0.f};

  const _Float16* Ab = A + (size_t)m0 * K;
  const _Float16* Bb = Bt + (size_t)n0 * K;

  for (int k0 = 0; k0 < K; k0 += 64) {
    #pragma unroll
    for (int q = 0; q < 4; ++q) {
      int off = ((w << 2) + q) << 10;
      int row = (off >> 7) + (lane >> 3);
      int sl  = (lane & 7) ^ (row & 7);
      gl_lds16(Ab + (size_t)row * K + k0 + (sl << 3), As + (off >> 1));
    }
    #pragma unroll
    for (int q = 0; q < 4; ++q) {
      int off = ((w << 2) + q) << 10;
      int row = (off >> 7) + (lane >> 3);
      int sl  = (lane & 7) ^ (row & 7);
      gl_lds16(Bb + (size_t)row * K + k0 + (sl << 3), Bs + (off >> 1));
    }
    __syncthreads();

    #pragma unroll
    for (int kk = 0; kk < 2; ++kk) {
      half8_t af[4], bf[4];
      #pragma unroll
      for (int mi = 0; mi < 4; ++mi) {
        int row = wr * 64 + mi * 16 + (lane & 15);
        int sl  = ((kk << 2) + (lane >> 4)) ^ (row & 7);
        af[mi] = *(const half8_t*)(As + row * 64 + (sl << 3));
      }
      #pragma unroll
      for (int ni = 0; ni < 4; ++ni) {
        int row = wc * 64 + ni * 16 + (lane & 15);
        int sl  = ((kk << 2) + (lane >> 4)) ^ (row & 7);
        bf[ni] = *(const half8_t*)(Bs + row * 64 + (sl << 3));
      }
      #pragma unroll
      for (int mi = 0; mi < 4; ++mi)
        #pragma unroll
        for (int ni = 0; ni < 4; ++ni)
          acc[mi][ni] = __builtin_amdgcn_mfma_f32_16x16x32_f16(
              bf[ni], af[mi], acc[mi][ni], 0, 0, 0);   // swapped: N on reg axis
    }
    __syncthreads();
  }

  int seg = n0 >> segShift; if (seg > 2) seg = 2;
  const float* bias = seg == 0 ? bs0 : (seg == 1 ? bs1 : bs2);
  const unsigned bmask = (segShift >= 31) ? 0xffffffffu : ((1u << segShift) - 1u);

  #pragma unroll
  for (int ni = 0; ni < 4; ++ni) {
    int n = n0 + wc * 64 + ni * 16 + ((lane >> 4) << 2);
    f32x4_t b4 = *(const f32x4_t*)(bias + (n & bmask));
    #pragma unroll
    for (int mi = 0; mi < 4; ++mi) {
      int m = m0 + wr * 64 + mi * 16 + (lane & 15);
      f32x4_t v = acc[mi][ni] + b4;
      if (DOGELU) {
        #pragma unroll
        for (int r = 0; r < 4; ++r)
          v[r] = 0.5f * v[r] * (1.f + erff(v[r] * 0.70710678118654752f));
      }
      if (OUT16) {
        half4_t o;
        o[0] = (_Float16)v[0]; o[1] = (_Float16)v[1];
        o[2] = (_Float16)v[2]; o[3] = (_Float16)v[3];
        *(half4_t*)((_Float16*)outp + (size_t)m * N + n) = o;
      } else {
        *(f32x4_t*)((float*)outp + (size_t)m * N + n) = v;
      }
    }
  }
}

// ---------------------------------------------------------------------------
// Autocorrelation v5 (proven best, 101 us): block owns (b,h,tau-window
// [64T,64T+64)). 64x64x4096 band GEMM accumulated in registers across 64
// J-tiles (2x2 wave quadrants), double-buffered staging, hoisted addressing.
// Diagonal extraction once per block. No atomics.
// ---------------------------------------------------------------------------
__global__ __launch_bounds__(256) void corr_gram5(
    const _Float16* __restrict__ QKV,
    float* __restrict__ corrP, float* __restrict__ corrN)
{
  __shared__ __attribute__((aligned(16))) char smem[34816];
  _Float16* Qs0 = (_Float16*)smem;            // [4096] halfs
  _Float16* Qs1 = Qs0 + 4096;
  _Float16* Ks0 = Qs0 + 8192;
  _Float16* Ks1 = Qs0 + 12288;
  float*    Gd  = (float*)smem;               // [128][68] after loop

  const int tid = threadIdx.x, lane = tid & 63, w = tid >> 6;
  const int p  = blockIdx.x;
  const int lg = ((p & 7) << 8) + (p >> 3);   // XCD-chunked swizzle
  const int T = lg & 63, h = (lg >> 6) & 7, b = lg >> 9;
  const int qr = w >> 1, qc = w & 1;

  // ---- hoisted per-thread staging offsets (2 issues each for Q and K)
  size_t qoff[2], koff[2]; int loff[2];
  #pragma unroll
  for (int q_ = 0; q_ < 2; ++q_) {
    int off_ = ((w << 1) + q_) << 10;
    int row_ = (off_ >> 7) + (lane >> 3);
    int sl_  = (lane & 7) ^ (row_ & 7);
    loff[q_] = off_ >> 1;
    qoff[q_] = (size_t)row_ * 1536 + (sl_ << 3) + h * 64;
    koff[q_] = qoff[q_] + 512;
  }
  const size_t bbase = (size_t)b * 4096 * 1536;

  // ---- hoisted frag LDS offsets (halfs)
  int aoff[2][2], boff[2][2];
  #pragma unroll
  for (int mi = 0; mi < 2; ++mi) {
    int row = (qr << 5) + (mi << 4) + (lane & 15);
    #pragma unroll
    for (int kk = 0; kk < 2; ++kk) {
      int sl = ((kk << 2) + (lane >> 4)) ^ (row & 7);
      aoff[mi][kk] = row * 64 + (sl << 3);
    }
  }
  #pragma unroll
  for (int ni = 0; ni < 2; ++ni) {
    int row = (qc << 5) + (ni << 4) + (lane & 15);
    #pragma unroll
    for (int kk = 0; kk < 2; ++kk) {
      int sl = ((kk << 2) + (lane >> 4)) ^ (row & 7);
      boff[ni][kk] = row * 64 + (sl << 3);
    }
  }

  f32x4_t acc[2][2];
  #pragma unroll
  for (int i = 0; i < 2; ++i)
    #pragma unroll
    for (int j = 0; j < 2; ++j) acc[i][j] = (f32x4_t){0.f, 0.f, 0.f, 0.f};

  auto stage = [&](_Float16* Qd, _Float16* Kd, int qt, int kt) {
    const size_t qb = bbase + (size_t)qt * 98304;   // 64*1536
    const size_t kb = bbase + (size_t)kt * 98304;
    #pragma unroll
    for (int q_ = 0; q_ < 2; ++q_) {
      gl_lds16(QKV + qb + qoff[q_], Qd + loff[q_]);
      gl_lds16(QKV + kb + koff[q_], Kd + loff[q_]);
    }
  };
  auto compute = [&](const _Float16* Qb, const _Float16* Kb) {
    half8_t a[2][2], bfr[2][2];
    #pragma unroll
    for (int mi = 0; mi < 2; ++mi)
      #pragma unroll
      for (int kk = 0; kk < 2; ++kk)
        a[mi][kk] = *(const half8_t*)(Qb + aoff[mi][kk]);
    #pragma unroll
    for (int ni = 0; ni < 2; ++ni)
      #pragma unroll
      for (int kk = 0; kk < 2; ++kk)
        bfr[ni][kk] = *(const half8_t*)(Kb + boff[ni][kk]);
    #pragma unroll
    for (int mi = 0; mi < 2; ++mi)
      #pragma unroll
      for (int ni = 0; ni < 2; ++ni) {
        acc[mi][ni] = __builtin_amdgcn_mfma_f32_16x16x32_f16(
            a[mi][0], bfr[ni][0], acc[mi][ni], 0, 0, 0);
        acc[mi][ni] = __builtin_amdgcn_mfma_f32_16x16x32_f16(
            a[mi][1], bfr[ni][1], acc[mi][ni], 0, 0, 0);
      }
  };

  stage(Qs0, Ks0, T, 0);
  __syncthreads();
  for (int J = 0; J < 64; J += 2) {
    stage(Qs1, Ks1, (T + J + 1) & 63, J + 1);
    compute(Qs0, Ks0);
    __syncthreads();                     // reads done + Qs1/Ks1 landed
    if (J + 2 < 64) stage(Qs0, Ks0, (T + J + 2) & 63, J + 2);
    compute(Qs1, Ks1);
    __syncthreads();
  }

  // ---- once-per-block diagonal extraction (Gd aliases stage buffers)
  for (int i = tid; i < 128 * 68; i += 256) Gd[i] = 0.f;
  __syncthreads();
  #pragma unroll
  for (int mi = 0; mi < 2; ++mi)
    #pragma unroll
    for (int ni = 0; ni < 2; ++ni)
      #pragma unroll
      for (int r = 0; r < 4; ++r) {
        int row = (qr << 5) + (mi << 4) + ((lane >> 4) << 2) + r;
        int col = (qc << 5) + (ni << 4) + (lane & 15);
        Gd[(row - col + 64) * 68 + col] = acc[mi][ni][r];
      }
  __syncthreads();

  float s;
  {
    const float* gp = &Gd[(tid >> 1) * 68 + ((tid & 1) << 5)];
    f32x4_t x0 = *(const f32x4_t*)gp        + *(const f32x4_t*)(gp + 4);
    f32x4_t x1 = *(const f32x4_t*)(gp + 8)  + *(const f32x4_t*)(gp + 12);
    f32x4_t x2 = *(const f32x4_t*)(gp + 16) + *(const f32x4_t*)(gp + 20);
    f32x4_t x3 = *(const f32x4_t*)(gp + 24) + *(const f32x4_t*)(gp + 28);
    x0 += x1; x2 += x3; x0 += x2;
    s = x0[0] + x0[1] + x0[2] + x0[3];
  }
  s += __shfl_xor(s, 1);
  if ((tid & 1) == 0) {
    const size_t bh = (size_t)(b * 8 + h) << 12;
    int v = tid >> 1;
    if (v == 0) {
      corrN[bh + (T << 6)] = 0.f;          // tau==0 mod 64: no negative part
    } else {
      int d = v - 64;
      int tau = ((T << 6) + d) & 4095;
      if (d >= 0) corrP[bh + tau] = s;
      else        corrN[bh + tau] = s;
    }
  }
}

// ---------------------------------------------------------------------------
// Top-8 + softmax per (b,h). corr = corrP + corrN. Lowest-index tie-break.
// ---------------------------------------------------------------------------
__global__ __launch_bounds__(256) void topk_softmax(
    const float* __restrict__ corrP, const float* __restrict__ corrN,
    float* __restrict__ tw, int* __restrict__ ti)
{
  __shared__ float vals[4096];
  __shared__ float wvv[4]; __shared__ int wii[4];
  __shared__ float rv[8]; __shared__ int ri[8];
  const int tid = threadIdx.x;
  const int bh = blockIdx.x;
  const float* cp = corrP + (size_t)bh * 4096;
  const float* cn = corrN + (size_t)bh * 4096;
  for (int i = tid; i < 4096; i += 256) vals[i] = cp[i] + cn[i];
  __syncthreads();

  for (int it = 0; it < 8; ++it) {
    float bv = -3.4e38f; int bi = 1 << 30;
    for (int i = tid; i < 4096; i += 256) {
      float v = vals[i];
      if (v > bv) { bv = v; bi = i; }
    }
    #pragma unroll
    for (int o = 32; o > 0; o >>= 1) {
      float ov = __shfl_down(bv, o);
      int   oi = __shfl_down(bi, o);
      if (ov > bv || (ov == bv && oi < bi)) { bv = ov; bi = oi; }
    }
    if ((tid & 63) == 0) { wvv[tid >> 6] = bv; wii[tid >> 6] = bi; }
    __syncthreads();
    if (tid == 0) {
      for (int k = 1; k < 4; ++k)
        if (wvv[k] > bv || (wvv[k] == bv && wii[k] < bi)) { bv = wvv[k]; bi = wii[k]; }
      rv[it] = bv; ri[it] = bi; vals[bi] = -3.4e38f;
    }
    __syncthreads();
  }

  if (tid == 0) {
    float m = rv[0] * (1.f / 64.f);          // corr_mean = corr/dk; rv[0] is max
    float e[8]; float s = 0.f;
    for (int k = 0; k < 8; ++k) { e[k] = expf(rv[k] * (1.f / 64.f) - m); s += e[k]; }
    float inv = 1.f / s;
    for (int k = 0; k < 8; ++k) { tw[bh * 8 + k] = e[k] * inv; ti[bh * 8 + k] = ri[k]; }
  }
}

// ---------------------------------------------------------------------------
// out[b,l,h*64+d] = sum_k tw[k] * V[b,(l+ti[k])%L, h*64+d]; V inside QKV
// (stride 1536, col offset 1024). Output fp16 [16384][512].
// ---------------------------------------------------------------------------
__global__ __launch_bounds__(256) void gather_attn(
    const _Float16* __restrict__ QKV, const float* __restrict__ tw,
    const int* __restrict__ ti, _Float16* __restrict__ outp)
{
  const int tid = threadIdx.x;
  const int d4 = tid & 127;
  const int r  = (blockIdx.x << 1) + (tid >> 7);
  const int b  = r >> 12, l = r & 4095;
  const int h  = d4 >> 4;
  const float* w8 = tw + (((b << 3) + h) << 3);
  const int*   i8 = ti + (((b << 3) + h) << 3);
  f32x4_t acc = (f32x4_t){0.f, 0.f, 0.f, 0.f};
  #pragma unroll
  for (int k = 0; k < 8; ++k) {
    int ls = (l + i8[k]) & 4095;
    half4_t v = *(const half4_t*)(QKV + ((size_t)((b << 12) + ls)) * 1536 + 1024 + (d4 << 2));
    float wk = w8[k];
    acc[0] += (float)v[0] * wk; acc[1] += (float)v[1] * wk;
    acc[2] += (float)v[2] * wk; acc[3] += (float)v[3] * wk;
  }
  half4_t o;
  o[0] = (_Float16)acc[0]; o[1] = (_Float16)acc[1];
  o[2] = (_Float16)acc[2]; o[3] = (_Float16)acc[3];
  *(half4_t*)(outp + ((size_t)r << 9) + (d4 << 2)) = o;
}

// ---------------------------------------------------------------------------
// y(fp16) = LayerNorm(xa + xb) * g + be ; xa/xb dtype per template.
// ---------------------------------------------------------------------------
template<int XA16, int XB16>
__global__ __launch_bounds__(256) void ln_add16(
    const void* __restrict__ xa, const void* __restrict__ xb,
    const float* __restrict__ g, const float* __restrict__ be,
    _Float16* __restrict__ y)
{
  const int lane = threadIdx.x & 63;
  const int row  = (blockIdx.x << 2) + (threadIdx.x >> 6);
  const size_t base = ((size_t)row << 9) + (lane << 3);
  f32x4_t a0, a1, b0, b1;
  if (XA16) {
    half8_t v = *(const half8_t*)((const _Float16*)xa + base);
    a0[0]=(float)v[0]; a0[1]=(float)v[1]; a0[2]=(float)v[2]; a0[3]=(float)v[3];
    a1[0]=(float)v[4]; a1[1]=(float)v[5]; a1[2]=(float)v[6]; a1[3]=(float)v[7];
  } else {
    const float* ar = (const float*)xa + base;
    a0 = *(const f32x4_t*)ar; a1 = *(const f32x4_t*)(ar + 4);
  }
  if (XB16) {
    half8_t v = *(const half8_t*)((const _Float16*)xb + base);
    b0[0]=(float)v[0]; b0[1]=(float)v[1]; b0[2]=(float)v[2]; b0[3]=(float)v[3];
    b1[0]=(float)v[4]; b1[1]=(float)v[5]; b1[2]=(float)v[6]; b1[3]=(float)v[7];
  } else {
    const float* br = (const float*)xb + base;
    b0 = *(const f32x4_t*)br; b1 = *(const f32x4_t*)(br + 4);
  }
  f32x4_t v0 = a0 + b0, v1 = a1 + b1;
  float s  = v0[0] + v0[1] + v0[2] + v0[3] + v1[0] + v1[1] + v1[2] + v1[3];
  float s2 = v0[0]*v0[0] + v0[1]*v0[1] + v0[2]*v0[2] + v0[3]*v0[3]
           + v1[0]*v1[0] + v1[1]*v1[1] + v1[2]*v1[2] + v1[3]*v1[3];
  #pragma unroll
  for (int o = 1; o < 64; o <<= 1) { s += __shfl_xor(s, o); s2 += __shfl_xor(s2, o); }
  float mu  = s * (1.f / 512.f);
  float var = s2 * (1.f / 512.f) - mu * mu;
  float rs  = rsqrtf(var + 1e-5f);
  const float* gr  = g  + (lane << 3);
  const float* ber = be + (lane << 3);
  f32x4_t g0 = *(const f32x4_t*)gr,  g1v = *(const f32x4_t*)(gr + 4);
  f32x4_t e0 = *(const f32x4_t*)ber, e1  = *(const f32x4_t*)(ber + 4);
  half8_t o8;
  #pragma unroll
  for (int i = 0; i < 4; ++i) {
    o8[i]     = (_Float16)((v0[i] - mu) * rs * g0[i]  + e0[i]);
    o8[4 + i] = (_Float16)((v1[i] - mu) * rs * g1v[i] + e1[i]);
  }
  *(half8_t*)(y + base) = o8;
}

// ---------------------------------------------------------------------------
// Series decomposition from fp16 y: moving average window 25, edge-replicated.
// MODE 1: seasonal fp16 + trend fp32 (overwrite)
// MODE 2: seasonal fp32 (d_out) + trendOut += trend
// ---------------------------------------------------------------------------
template<int MODE>
__global__ __launch_bounds__(256) void movavg16(
    const _Float16* __restrict__ y, float* __restrict__ seasF,
    _Float16* __restrict__ seasH, float* __restrict__ trendOut)
{
  __shared__ float T[152 * 64];
  const int lt = blockIdx.x, dc = blockIdx.y, b = blockIdx.z;
  const int l0 = lt << 7, d0 = dc << 6;
  const int tid = threadIdx.x;
  for (int idx = tid; idx < 152 * 8; idx += 256) {
    int rr = idx >> 3, c8 = idx & 7;
    int ls = l0 - 12 + rr;
    ls = ls < 0 ? 0 : (ls > 4095 ? 4095 : ls);
    half8_t v = *(const half8_t*)(y + (((size_t)(b << 12) + ls) << 9) + d0 + (c8 << 3));
    float* tp = &T[rr * 64 + (c8 << 3)];
    f32x4_t lo, hi;
    lo[0]=(float)v[0]; lo[1]=(float)v[1]; lo[2]=(float)v[2]; lo[3]=(float)v[3];
    hi[0]=(float)v[4]; hi[1]=(float)v[5]; hi[2]=(float)v[6]; hi[3]=(float)v[7];
    *(f32x4_t*)tp = lo; *(f32x4_t*)(tp + 4) = hi;
  }
  __syncthreads();
  for (int idx = tid; idx < 128 * 16; idx += 256) {
    int rr = idx >> 4, c4 = idx & 15;
    f32x4_t s = (f32x4_t){0.f, 0.f, 0.f, 0.f};
    #pragma unroll
    for (int j = 0; j < 25; ++j) s += *(const f32x4_t*)&T[(rr + j) * 64 + (c4 << 2)];
    f32x4_t trend = s * (1.f / 25.f);
    f32x4_t ctr   = *(const f32x4_t*)&T[(rr + 12) * 64 + (c4 << 2)];
    f32x4_t seas  = ctr - trend;
    size_t gp = (((size_t)(b << 12) + l0 + rr) << 9) + d0 + (c4 << 2);
    if (MODE == 1) {
      half4_t sh;
      sh[0] = (_Float16)seas[0]; sh[1] = (_Float16)seas[1];
      sh[2] = (_Float16)seas[2]; sh[3] = (_Float16)seas[3];
      *(half4_t*)(seasH + gp) = sh;
      *(f32x4_t*)(trendOut + gp) = trend;
    } else {
      *(f32x4_t*)(seasF + gp) = seas;
      f32x4_t t1 = *(const f32x4_t*)(trendOut + gp);
      t1 += trend;
      *(f32x4_t*)(trendOut + gp) = t1;
    }
  }
}

// ---------------------------------------------------------------------------
// Prep (one dispatch): x fp32->fp16 convert + all weight transposes.
// Q/K/V transposed into ONE fused [1536][512] fp16 buffer.
// ---------------------------------------------------------------------------
__global__ __launch_bounds__(256) void prep_all(
    const float* __restrict__ x, _Float16* __restrict__ X16,
    const float* __restrict__ Wq, const float* __restrict__ Wk,
    const float* __restrict__ Wv, const float* __restrict__ Wo,
    const float* __restrict__ W1, const float* __restrict__ W2,
    _Float16* __restrict__ WQKVT, _Float16* __restrict__ WOT,
    _Float16* __restrict__ W1T, _Float16* __restrict__ W2T)
{
  const int bid = blockIdx.x;
  if (bid < 8192) {
    int i = bid * 256 + threadIdx.x;
    f32x4_t v = *(const f32x4_t*)(x + ((size_t)i << 2));
    half4_t o;
    o[0] = (_Float16)v[0]; o[1] = (_Float16)v[1];
    o[2] = (_Float16)v[2]; o[3] = (_Float16)v[3];
    *(half4_t*)(X16 + ((size_t)i << 2)) = o;
    return;
  }
  const int id = bid - 8192;
  const float* src; _Float16* dst; int Kd, Nd, kb, nb, nbase;
  if (id < 1024) {
    int wsel = id >> 8, r = id & 255;
    kb = (r & 15) << 5; nb = (r >> 4) << 5; Kd = 512; Nd = 512;
    src = wsel == 0 ? Wq : wsel == 1 ? Wk : wsel == 2 ? Wv : Wo;
    if (wsel < 3) { dst = WQKVT; nbase = (wsel << 9) + nb; }
    else          { dst = WOT;   nbase = nb; }
  } else if (id < 2048) {
    int r = id - 1024;
    kb = (r & 15) << 5; nb = (r >> 4) << 5; Kd = 512; Nd = 2048;
    src = W1; dst = W1T; nbase = nb;
  } else {
    int r = id - 2048;
    kb = (r & 63) << 5; nb = (r >> 6) << 5; Kd = 2048; Nd = 512;
    src = W2; dst = W2T; nbase = nb;
  }
  __shared__ float t[32][33];
  const int tx = threadIdx.x & 31, ty = threadIdx.x >> 5;
  #pragma unroll
  for (int r0 = 0; r0 < 32; r0 += 8)
    t[ty + r0][tx] = src[(size_t)(kb + ty + r0) * Nd + nb + tx];
  __syncthreads();
  #pragma unroll
  for (int r0 = 0; r0 < 32; r0 += 8)
    dst[(size_t)(nbase + ty + r0) * Kd + kb + tx] = (_Float16)t[tx][ty + r0];
}

// ---------------------------------------------------------------------------
extern "C" void kernel_launch(void* const* d_in, const int* in_sizes, int n_in,
                              void* d_out, int out_size, void* d_ws, size_t ws_size,
                              hipStream_t stream)
{
  const float* x   = (const float*)d_in[0];
  const float* Wq  = (const float*)d_in[1];
  const float* bq  = (const float*)d_in[2];
  const float* Wk  = (const float*)d_in[3];
  const float* bk  = (const float*)d_in[4];
  const float* Wv  = (const float*)d_in[5];
  const float* bv  = (const float*)d_in[6];
  const float* Wo  = (const float*)d_in[7];
  const float* bo  = (const float*)d_in[8];
  const float* W1  = (const float*)d_in[9];
  const float* b1  = (const float*)d_in[10];
  const float* W2  = (const float*)d_in[11];
  const float* b2  = (const float*)d_in[12];
  const float* g1  = (const float*)d_in[13];
  const float* be1 = (const float*)d_in[14];
  const float* g2  = (const float*)d_in[15];
  const float* be2 = (const float*)d_in[16];

  char* ws = (char*)d_ws;
  constexpr size_t ME = 16384ull * 512ull;                 // 8,388,608 elems
  constexpr size_t OFF_X16   = 0;                          // 16.78 MB fp16
  constexpr size_t OFF_WQKVT = OFF_X16 + 2 * ME;           // 1536x512 fp16
  constexpr size_t OFF_WOT   = OFF_WQKVT + 1536 * 512 * 2;
  constexpr size_t OFF_W1T   = OFF_WOT + 512 * 512 * 2;
  constexpr size_t OFF_W2T   = OFF_W1T + 2048 * 512 * 2;
  constexpr size_t OFF_QKV16 = OFF_W2T + 2048 * 512 * 2;   // 50.33 MB [16384][1536] fp16
  constexpr size_t OFF_ATTN16= OFF_QKV16 + 6 * ME;         // 16.78 MB fp16
  constexpr size_t OFF_FF16  = OFF_ATTN16 + 2 * ME;        // 16.78 MB fp16
  constexpr size_t OFF_CORRP = OFF_FF16 + 2 * ME;          // 0.52 MB
  constexpr size_t OFF_CORRN = OFF_CORRP + 32 * 4096 * 4;  // 0.52 MB
  constexpr size_t OFF_TW    = OFF_CORRN + 32 * 4096 * 4;
  constexpr size_t OFF_TI    = OFF_TW + 1024;
  // aliases (lifetime-disjoint reuse)
  constexpr size_t OFF_AIN16 = OFF_X16;    // gather out (X16 dead after QKV gemm)
  constexpr size_t OFF_S116  = OFF_X16;    // seasonal1 fp16 (AIN16 dead after O-proj)
  constexpr size_t OFF_Y116  = OFF_QKV16;  // QKV dead after gather
  constexpr size_t OFF_H16   = OFF_QKV16;  // 67.1 MB spans QKV16+ATTN16 (both dead pre-FFN1)
  constexpr size_t OFF_Y216  = OFF_QKV16;  // H16 dead after FFN2

  _Float16* X16   = (_Float16*)(ws + OFF_X16);
  _Float16* WQKVT = (_Float16*)(ws + OFF_WQKVT);
  _Float16* WOT   = (_Float16*)(ws + OFF_WOT);
  _Float16* W1T   = (_Float16*)(ws + OFF_W1T);
  _Float16* W2T   = (_Float16*)(ws + OFF_W2T);
  _Float16* QKV16 = (_Float16*)(ws + OFF_QKV16);
  _Float16* ATTN16= (_Float16*)(ws + OFF_ATTN16);
  _Float16* FF16  = (_Float16*)(ws + OFF_FF16);
  float*    CORRP = (float*)(ws + OFF_CORRP);
  float*    CORRN = (float*)(ws + OFF_CORRN);
  float*    TW    = (float*)(ws + OFF_TW);
  int*      TI    = (int*)(ws + OFF_TI);
  _Float16* AIN16 = (_Float16*)(ws + OFF_AIN16);
  _Float16* S116  = (_Float16*)(ws + OFF_S116);
  _Float16* H16   = (_Float16*)(ws + OFF_H16);
  _Float16* Y116  = (_Float16*)(ws + OFF_Y116);
  _Float16* Y216  = (_Float16*)(ws + OFF_Y216);

  float* OUT_SEAS  = (float*)d_out;            // seasonal2
  float* OUT_TREND = (float*)d_out + ME;       // trend1 + trend2

  // --- prep (convert + transposes, one dispatch) ---
  prep_all<<<11264, 256, 0, stream>>>(x, X16, Wq, Wk, Wv, Wo, W1, W2,
                                      WQKVT, WOT, W1T, W2T);

  // --- fused QKV projection: [16384,1536] = X16 @ WQKVT^T ---
  gemm_f16k<true, false><<<1536, 256, 0, stream>>>(
      X16, WQKVT, bq, bk, bv, 9, QKV16, 16384, 1536, 512, 12);

  // --- autocorrelation ---
  corr_gram5<<<2048, 256, 0, stream>>>(QKV16, CORRP, CORRN);
  topk_softmax<<<32, 256, 0, stream>>>(CORRP, CORRN, TW, TI);
  gather_attn<<<8192, 256, 0, stream>>>(QKV16, TW, TI, AIN16);
  gemm_f16k<true, false><<<512, 256, 0, stream>>>(
      AIN16, WOT, bo, bo, bo, 31, ATTN16, 16384, 512, 512, 4);

  // --- LN1 + decomp1 ---
  ln_add16<0, 1><<<4096, 256, 0, stream>>>(x, ATTN16, g1, be1, Y116);
  movavg16<1><<<dim3(32, 8, 4), 256, 0, stream>>>(Y116, nullptr, S116, OUT_TREND);

  // --- FFN ---
  gemm_f16k<true, true ><<<2048, 256, 0, stream>>>(
      S116, W1T, b1, b1, b1, 31, H16, 16384, 2048, 512, 16);
  gemm_f16k<true, false><<<512, 256, 0, stream>>>(
      H16, W2T, b2, b2, b2, 31, FF16, 16384, 512, 2048, 4);

  // --- LN2 + decomp2 ---
  ln_add16<1, 1><<<4096, 256, 0, stream>>>(S116, FF16, g2, be2, Y216);
  movavg16<2><<<dim3(32, 8, 4), 256, 0, stream>>>(Y216, OUT_SEAS, nullptr, OUT_TREND);
}